// Round 12
// baseline (185.072 us; speedup 1.0000x reference)
//
#include <hip/hip_runtime.h>
#include <hip/hip_bf16.h>

#define B_   8
#define S_   1024
#define H_   768
#define NH_  12
#define DK_  64
#define M_   (B_ * S_)   // 8192

typedef __attribute__((ext_vector_type(8))) short          short8;
typedef __attribute__((ext_vector_type(8))) unsigned short ushort8;
typedef __attribute__((ext_vector_type(4))) unsigned short ushort4v;
typedef __attribute__((ext_vector_type(4))) float          f32x4;

__device__ __forceinline__ unsigned short f2bf(float x) {
    union { __hip_bfloat16 h; unsigned short u; } r;
    r.h = __float2bfloat16(x);
    return r.u;
}

__device__ __forceinline__ unsigned cvtpk_bf16(float lo, float hi) {
    unsigned r;
    asm("v_cvt_pk_bf16_f32 %0, %1, %2" : "=v"(r) : "v"(lo), "v"(hi));
    return r;
}

__device__ __forceinline__ void glds16(const unsigned short* g, unsigned short* l) {
    __builtin_amdgcn_global_load_lds(
        (const __attribute__((address_space(1))) unsigned int*)g,
        (__attribute__((address_space(3))) unsigned int*)l, 16, 0, 0);
}

// ---------------------------------------------------------------------------
// One-shot convert of the 4 weight matrices to bf16 (Wq pre-scaled by
// log2(e)/sqrt(DK) so attention scores land directly in exp2 domain).
// ---------------------------------------------------------------------------
__global__ __launch_bounds__(256)
void cvt_w(const float* __restrict__ w0, const float* __restrict__ w1,
           const float* __restrict__ w2, const float* __restrict__ w3,
           unsigned short* __restrict__ o0, unsigned short* __restrict__ o1,
           unsigned short* __restrict__ o2, unsigned short* __restrict__ o3)
{
    const int wsel = blockIdx.y;
    const float* src = (wsel == 0) ? w0 : (wsel == 1) ? w1 : (wsel == 2) ? w2 : w3;
    unsigned short* dst = (wsel == 0) ? o0 : (wsel == 1) ? o1 : (wsel == 2) ? o2 : o3;
    const float s = (wsel == 0) ? 0.125f * 1.44269504089f : 1.0f;
    const int i = blockIdx.x * 256 + threadIdx.x;
    const float4 x = ((const float4*)src)[i];
    ushort4v o;
    o[0] = f2bf(x.x * s); o[1] = f2bf(x.y * s);
    o[2] = f2bf(x.z * s); o[3] = f2bf(x.w * s);
    ((ushort4v*)dst)[i] = o;
}

// ---------------------------------------------------------------------------
// y[M,N] = x[M,K] @ W[N,K]^T.  128x128 tile, BK=64 (12 iters), 4 waves x
// (4x4) frags, single-buffered 2-phase (round-10 schedule; dbuf reverted).
// LDS layout XOR-swizzled (T2): element (row, colblk) at colblk ^ (row&7),
// achieved with LINEAR DMA dest + PRE-SWIZZLED global source (rule #21);
// fragment ds_read_b128 at ((kk*4+lg) ^ (lc&7)) -> 2-way (free) banks.
// XCD-colocating 1D-grid swizzle (bid&7 -> XCD) kept.
// ---------------------------------------------------------------------------
template<bool A_BF16, bool OUT_BF16>
__global__ __launch_bounds__(256)
void gemm_bt(const void* __restrict__ A0, const void* __restrict__ A1,
             const void* __restrict__ A2,
             const unsigned short* __restrict__ W0,
             const unsigned short* __restrict__ W1,
             const unsigned short* __restrict__ W2,
             void* __restrict__ C0, void* __restrict__ C1, void* __restrict__ C2)
{
    __shared__ unsigned short As[128 * 64];   // 16 KB
    __shared__ unsigned short Bs[128 * 64];   // 16 KB

    const int tid  = threadIdx.x;
    const int bid  = blockIdx.x;
    const int x    = bid & 7, j = bid >> 3;
    const int z    = j / 48;            // 0..2 (QKV, grid 1152) or 0 (grid 384)
    const int r48  = j % 48;
    const int bm   = x * 8 + r48 / 6;
    const int bn   = r48 % 6;

    const int w    = tid >> 6, lane = tid & 63;
    const int lg   = lane >> 4, lc = lane & 15;
    const int wm   = (w >> 1) * 64, wn = (w & 1) * 64;

    const void* Av = (z == 0) ? A0 : (z == 1) ? A1 : A2;
    const unsigned short* Bw = (z == 0) ? W0 : (z == 1) ? W1 : W2;
    void* Cv = (z == 0) ? C0 : (z == 1) ? C1 : C2;

    const float*          Af = (const float*)Av;
    const unsigned short* Ah = (const unsigned short*)Av;

    // DMA staging: chunk c = w*4+i covers rows w*32+i*8 .. +8.  Lane l writes
    // linear colblk (l&7); its SOURCE colblk is (l&7)^(l>>3) so that the
    // element lands at its swizzled home cb^(row&7).
    const int srow8 = lane >> 3;
    const int scb   = (lane & 7) ^ srow8;
    const unsigned short* gB0 = &Bw[(size_t)(bn * 128 + w * 32 + srow8) * H_ + scb * 8];
    const unsigned short* gA0 = A_BF16 ?
        &Ah[(size_t)(bm * 128 + w * 32 + srow8) * H_ + scb * 8] : nullptr;

    // fp32-A staging: thread covers row tid>>1, colblks (tid&1)*4 .. +4,
    // ds_write directly to the swizzled home.
    const int arow  = tid >> 1;
    const int ahalf = tid & 1;
    const float* gAf = A_BF16 ? nullptr :
        &Af[(size_t)(bm * 128 + arow) * H_ + ahalf * 32];

    f32x4 acc[4][4] = {};

    for (int t = 0; t < H_ / 64; t++) {     // 12 iterations
        const int k0 = t * 64;

        // ---- stage: B (and A when bf16) via async DMA; A-fp32 via reg cvt ----
#pragma unroll
        for (int i = 0; i < 4; i++) {
            glds16(gB0 + (size_t)i * 8 * H_ + k0, &Bs[(w * 4 + i) * 512]);
            if (A_BF16)
                glds16(gA0 + (size_t)i * 8 * H_ + k0, &As[(w * 4 + i) * 512]);
        }
        if (!A_BF16) {
#pragma unroll
            for (int jj = 0; jj < 4; jj++) {
                const float4 x0 = *(const float4*)(gAf + k0 + jj * 8);
                const float4 x1 = *(const float4*)(gAf + k0 + jj * 8 + 4);
                ushort8 o8;
                o8[0] = f2bf(x0.x); o8[1] = f2bf(x0.y);
                o8[2] = f2bf(x0.z); o8[3] = f2bf(x0.w);
                o8[4] = f2bf(x1.x); o8[5] = f2bf(x1.y);
                o8[6] = f2bf(x1.z); o8[7] = f2bf(x1.w);
                *(ushort8*)&As[arow * 64 + (((ahalf * 4 + jj) ^ (arow & 7)) * 8)] = o8;
            }
        }
        __syncthreads();

        // ---- compute: 2 k-slices x 16 MFMA ----
#pragma unroll
        for (int kk = 0; kk < 2; kk++) {
            const int cbl = ((kk * 4 + lg) ^ (lc & 7)) * 8;
            short8 af[4], bfr[4];
#pragma unroll
            for (int mi = 0; mi < 4; mi++)
                af[mi] = *(const short8*)&As[(wm + mi * 16 + lc) * 64 + cbl];
#pragma unroll
            for (int ni = 0; ni < 4; ni++)
                bfr[ni] = *(const short8*)&Bs[(wn + ni * 16 + lc) * 64 + cbl];
            __builtin_amdgcn_s_setprio(1);
#pragma unroll
            for (int mi = 0; mi < 4; mi++)
#pragma unroll
                for (int ni = 0; ni < 4; ni++)
                    acc[mi][ni] = __builtin_amdgcn_mfma_f32_16x16x32_bf16(
                        af[mi], bfr[ni], acc[mi][ni], 0, 0, 0);
            __builtin_amdgcn_s_setprio(0);
        }
        __syncthreads();
    }

#pragma unroll
    for (int mi = 0; mi < 4; mi++)
#pragma unroll
        for (int ni = 0; ni < 4; ni++)
#pragma unroll
            for (int reg = 0; reg < 4; reg++) {
                const int row = bm * 128 + wm + mi * 16 + lg * 4 + reg;
                const int col = bn * 128 + wn + ni * 16 + lc;
                if (OUT_BF16)
                    ((unsigned short*)Cv)[(size_t)row * H_ + col] = f2bf(acc[mi][ni][reg]);
                else
                    ((float*)Cv)[(size_t)row * H_ + col] = acc[mi][ni][reg];
            }
}

// ---------------------------------------------------------------------------
// V transpose: vb[B,S,H] -> vt[B,NH,DK,S]  (per head: [key][d] -> [d][key]).
// ---------------------------------------------------------------------------
__global__ __launch_bounds__(256)
void transpose_v(const unsigned short* __restrict__ v,
                 unsigned short* __restrict__ vt)
{
    __shared__ unsigned short T[64][72];
    const int tid = threadIdx.x;
    const int st0 = blockIdx.x, h = blockIdx.y, b = blockIdx.z;
    const int r = tid >> 2, d0 = (tid & 3) * 16, g = tid & 3;

    const unsigned short* src = &v[(size_t)(b * S_ + st0 * 64 + r) * H_ + h * DK_ + d0];
    const ushort8 v0 = *(const ushort8*)src;
    const ushort8 v1 = *(const ushort8*)(src + 8);
    const int colv = r ^ (g << 4);
#pragma unroll
    for (int j = 0; j < 8; j++) T[d0 + j][colv]     = v0[j];
#pragma unroll
    for (int j = 0; j < 8; j++) T[d0 + 8 + j][colv] = v1[j];
    __syncthreads();

    const size_t ob = ((size_t)(b * NH_ + h) * DK_) * S_ + st0 * 64;
#pragma unroll
    for (int half = 0; half < 2; half++) {
        const int ci = half * 256 + tid;
        const int d = ci >> 3, kc = ci & 7;
        const int sw = ((d >> 4) & 3) << 4;
        const ushort8 val = *(const ushort8*)&T[d][(kc * 8) ^ sw];
        *(ushort8*)&vt[ob + (size_t)d * S_ + kc * 8] = val;
    }
}

// ---------------------------------------------------------------------------
// Flash attention v5 (round-9, unchanged — best measured ~49 us): K + V^T
// staged in LDS (vectorized, padded-72 conflict-free), swapped QK^T,
// static-max softmax (p = exp2(s)), lane-local l partials reduced once after
// the loop, cvt_pk P-pack + double-shuffle P-exchange.
// ---------------------------------------------------------------------------
__global__ __launch_bounds__(256)
void attn(const unsigned short* __restrict__ q,
          const unsigned short* __restrict__ k,
          const unsigned short* __restrict__ vt,
          unsigned short* __restrict__ c)
{
    __shared__ unsigned short Ks[64][72];
    __shared__ unsigned short Vs[64][72];   // Vs[d][key], direct rows of vt

    const int tid  = threadIdx.x;
    const int qt   = blockIdx.x, h = blockIdx.y, b = blockIdx.z;
    const int wid  = tid >> 6;
    const int lane = tid & 63;
    const int lg   = lane >> 4, lc = lane & 15;
    const int r    = tid >> 2;
    const int g    = tid & 3;
    const int d0   = g * 16;
    const size_t base = (size_t)b * S_ * H_ + (size_t)h * DK_;
    const size_t vtb  = (size_t)(b * NH_ + h) * DK_ * S_;

    short8 aq[2][2];
#pragma unroll
    for (int m = 0; m < 2; m++)
#pragma unroll
        for (int ks = 0; ks < 2; ks++)
            aq[m][ks] = *(const short8*)
                &q[base + (size_t)(qt * 128 + wid * 32 + m * 16 + lc) * H_ + ks * 32 + lg * 8];

    f32x4 o[2][4] = {};
    float lsum[2] = {0.f, 0.f};

    for (int kt = 0; kt < S_ / 64; kt++) {
        {
            const unsigned short* ksrc = &k[base + (size_t)(kt * 64 + r) * H_ + d0];
            *(ushort8*)&Ks[r][d0]     = *(const ushort8*)ksrc;
            *(ushort8*)&Ks[r][d0 + 8] = *(const ushort8*)(ksrc + 8);
            const unsigned short* vsrc = &vt[vtb + (size_t)r * S_ + kt * 64 + d0];
            *(ushort8*)&Vs[r][d0]     = *(const ushort8*)vsrc;
            *(ushort8*)&Vs[r][d0 + 8] = *(const ushort8*)(vsrc + 8);
        }
        __syncthreads();

        f32x4 st[2][4] = {};
        __builtin_amdgcn_s_setprio(1);
#pragma unroll
        for (int ni = 0; ni < 4; ni++)
#pragma unroll
            for (int ks = 0; ks < 2; ks++) {
                const short8 bk = *(const short8*)&Ks[ni * 16 + lc][ks * 32 + lg * 8];
                st[0][ni] = __builtin_amdgcn_mfma_f32_16x16x32_bf16(bk, aq[0][ks], st[0][ni], 0, 0, 0);
                st[1][ni] = __builtin_amdgcn_mfma_f32_16x16x32_bf16(bk, aq[1][ks], st[1][ni], 0, 0, 0);
            }
        __builtin_amdgcn_s_setprio(0);

        unsigned pw[2][4][2];
#pragma unroll
        for (int m = 0; m < 2; m++) {
#pragma unroll
            for (int ni = 0; ni < 4; ni++) {
#pragma unroll
                for (int reg = 0; reg < 4; reg++) {
                    const float pp = exp2f(st[m][ni][reg]);
                    st[m][ni][reg] = pp;
                    lsum[m] += pp;
                }
                pw[m][ni][0] = cvtpk_bf16(st[m][ni][0], st[m][ni][1]);
                pw[m][ni][1] = cvtpk_bf16(st[m][ni][2], st[m][ni][3]);
            }
        }

        const int sl0 = lc + ((lg & 1) << 5);
        const int sl1 = sl0 + 16;
        const bool hi = (lg >> 1) != 0;
        short8 pa[2][2];
#pragma unroll
        for (int m = 0; m < 2; m++)
#pragma unroll
            for (int ks = 0; ks < 2; ks++) {
                const unsigned lo0 = pw[m][2 * ks][0],     lo1 = pw[m][2 * ks][1];
                const unsigned hi0 = pw[m][2 * ks + 1][0], hi1 = pw[m][2 * ks + 1][1];
                union { unsigned u[4]; short8 s8; } pk;
                const unsigned a0l = __shfl(lo0, sl0, 64), a0h = __shfl(hi0, sl0, 64);
                const unsigned a1l = __shfl(lo1, sl0, 64), a1h = __shfl(hi1, sl0, 64);
                const unsigned a2l = __shfl(lo0, sl1, 64), a2h = __shfl(hi0, sl1, 64);
                const unsigned a3l = __shfl(lo1, sl1, 64), a3h = __shfl(hi1, sl1, 64);
                pk.u[0] = hi ? a0h : a0l;
                pk.u[1] = hi ? a1h : a1l;
                pk.u[2] = hi ? a2h : a2l;
                pk.u[3] = hi ? a3h : a3l;
                pa[m][ks] = pk.s8;
            }

        __builtin_amdgcn_s_setprio(1);
#pragma unroll
        for (int ni = 0; ni < 4; ni++)
#pragma unroll
            for (int ks = 0; ks < 2; ks++) {
                const short8 bv = *(const short8*)&Vs[ni * 16 + lc][ks * 32 + lg * 8];
                o[0][ni] = __builtin_amdgcn_mfma_f32_16x16x32_bf16(pa[0][ks], bv, o[0][ni], 0, 0, 0);
                o[1][ni] = __builtin_amdgcn_mfma_f32_16x16x32_bf16(pa[1][ks], bv, o[1][ni], 0, 0, 0);
            }
        __builtin_amdgcn_s_setprio(0);
        __syncthreads();
    }

#pragma unroll
    for (int m = 0; m < 2; m++) {
        float l = lsum[m];
        l += __shfl_xor(l, 16, 64);
        l += __shfl_xor(l, 32, 64);
        const float iv = 1.0f / l;
#pragma unroll
        for (int reg = 0; reg < 4; reg++) {
            const float ivr = __shfl(iv, lg * 4 + reg, 64);
            const int row = qt * 128 + wid * 32 + m * 16 + lg * 4 + reg;
#pragma unroll
            for (int ni = 0; ni < 4; ni++)
                c[base + (size_t)row * H_ + ni * 16 + lc] = f2bf(o[m][ni][reg] * ivr);
        }
    }
}

// ---------------------------------------------------------------------------
extern "C" void kernel_launch(void* const* d_in, const int* in_sizes, int n_in,
                              void* d_out, int out_size, void* d_ws, size_t ws_size,
                              hipStream_t stream)
{
    const float* Q  = (const float*)d_in[0];
    const float* K  = (const float*)d_in[1];
    const float* V  = (const float*)d_in[2];
    const float* Wq = (const float*)d_in[3];
    const float* Wk = (const float*)d_in[4];
    const float* Wv = (const float*)d_in[5];
    const float* Wo = (const float*)d_in[6];

    unsigned short* qb = (unsigned short*)d_ws;
    unsigned short* kb = qb + (size_t)M_ * H_;
    unsigned short* vb = kb + (size_t)M_ * H_;
    unsigned short* vtb = vb + (size_t)M_ * H_;   // transposed V
    unsigned short* cb  = vb;                      // vb dead after transpose
    unsigned short* wq = vtb + (size_t)M_ * H_;
    unsigned short* wk = wq + (size_t)H_ * H_;
    unsigned short* wv = wk + (size_t)H_ * H_;
    unsigned short* wo = wv + (size_t)H_ * H_;

    cvt_w<<<dim3(H_ * H_ / 4 / 256, 4), 256, 0, stream>>>(
        Wq, Wk, Wv, Wo, wq, wk, wv, wo);

    // fused QKV projections: 1152 blocks, XCD-swizzled inside the kernel
    gemm_bt<false, true><<<dim3(64 * 6 * 3), 256, 0, stream>>>(
        Q, K, V, wq, wk, wv, qb, kb, vb);

    transpose_v<<<dim3(S_ / 64, NH_, B_), 256, 0, stream>>>(vb, vtb);

    attn<<<dim3(S_ / 128, NH_, B_), 256, 0, stream>>>(qb, kb, vtb, cb);

    // output projection: 384 blocks (z = 0), bf16 A via global_load_lds
    gemm_bt<true, false><<<dim3(64 * 6), 256, 0, stream>>>(
        cb, cb, cb, wo, wo, wo, d_out, d_out, d_out);
}

// Round 13
// 153.479 us; speedup vs baseline: 1.2058x; 1.2058x over previous
//
#include <hip/hip_runtime.h>
#include <hip/hip_bf16.h>

#define B_   8
#define S_   1024
#define H_   768
#define NH_  12
#define DK_  64
#define M_   (B_ * S_)   // 8192

typedef __attribute__((ext_vector_type(8))) short          short8;
typedef __attribute__((ext_vector_type(8))) unsigned short ushort8;
typedef __attribute__((ext_vector_type(4))) unsigned short ushort4v;
typedef __attribute__((ext_vector_type(4))) float          f32x4;

__device__ __forceinline__ unsigned short f2bf(float x) {
    union { __hip_bfloat16 h; unsigned short u; } r;
    r.h = __float2bfloat16(x);
    return r.u;
}

__device__ __forceinline__ unsigned cvtpk_bf16(float lo, float hi) {
    unsigned r;
    asm("v_cvt_pk_bf16_f32 %0, %1, %2" : "=v"(r) : "v"(lo), "v"(hi));
    return r;
}

__device__ __forceinline__ void glds16(const unsigned short* g, unsigned short* l) {
    __builtin_amdgcn_global_load_lds(
        (const __attribute__((address_space(1))) unsigned int*)g,
        (__attribute__((address_space(3))) unsigned int*)l, 16, 0, 0);
}

// ---------------------------------------------------------------------------
// One-shot convert of the 4 weight matrices to bf16 (Wq pre-scaled by
// log2(e)/sqrt(DK) so attention scores land directly in exp2 domain).
// ---------------------------------------------------------------------------
__global__ __launch_bounds__(256)
void cvt_w(const float* __restrict__ w0, const float* __restrict__ w1,
           const float* __restrict__ w2, const float* __restrict__ w3,
           unsigned short* __restrict__ o0, unsigned short* __restrict__ o1,
           unsigned short* __restrict__ o2, unsigned short* __restrict__ o3)
{
    const int wsel = blockIdx.y;
    const float* src = (wsel == 0) ? w0 : (wsel == 1) ? w1 : (wsel == 2) ? w2 : w3;
    unsigned short* dst = (wsel == 0) ? o0 : (wsel == 1) ? o1 : (wsel == 2) ? o2 : o3;
    const float s = (wsel == 0) ? 0.125f * 1.44269504089f : 1.0f;
    const int i = blockIdx.x * 256 + threadIdx.x;
    const float4 x = ((const float4*)src)[i];
    ushort4v o;
    o[0] = f2bf(x.x * s); o[1] = f2bf(x.y * s);
    o[2] = f2bf(x.z * s); o[3] = f2bf(x.w * s);
    ((ushort4v*)dst)[i] = o;
}

// ---------------------------------------------------------------------------
// y[M,N] = x[M,K] @ W[N,K]^T.  128x128 tile, BK=32, 4 waves x (4x4) frags.
// PREFETCHED 2-phase, STATICALLY-NAMED double buffers (round-11's dbuf
// failed because As[2][..] indexed by runtime `buf` defeated alias analysis
// -> compiler drained vmcnt BEFORE compute; distinct arrays + manually
// unrolled 2-step body keep the drain at the barrier, after compute).
// Per phase: ISSUE(next tile: B via async DMA, A-fp32 -> regs+cvt) ->
// COMPUTE(current) -> WRITE_A(next) -> barrier.   [T3-minimum + T14]
// XCD-colocating 1D-grid swizzle (bid&7 -> XCD) kept.
// ---------------------------------------------------------------------------
#define GEMM_ISSUE(AsX, BsX, k0)                                              \
  {                                                                           \
    glds16(gB + (k0), (BsX) + w * 512);                                       \
    glds16(gB + (size_t)64 * H_ + (k0), (BsX) + 2048 + w * 512);              \
    if (A_BF16) {                                                             \
      glds16(gAh + (k0), (AsX) + w * 512);                                    \
      glds16(gAh + (size_t)64 * H_ + (k0), (AsX) + 2048 + w * 512);           \
    } else {                                                                  \
      _Pragma("unroll")                                                       \
      for (int i = 0; i < 2; i++) {                                           \
        const float4 x0 = *(const float4*)(gAf + (size_t)i * 64 * H_ + (k0));  \
        const float4 x1 = *(const float4*)(gAf + (size_t)i * 64 * H_ + (k0) + 4);\
        ushort8 o8;                                                           \
        o8[0] = f2bf(x0.x); o8[1] = f2bf(x0.y);                               \
        o8[2] = f2bf(x0.z); o8[3] = f2bf(x0.w);                               \
        o8[4] = f2bf(x1.x); o8[5] = f2bf(x1.y);                               \
        o8[6] = f2bf(x1.z); o8[7] = f2bf(x1.w);                               \
        a8[i] = o8;                                                           \
      }                                                                       \
    }                                                                         \
  }

#define GEMM_WRITE_A(AsX)                                                     \
  if (!A_BF16) {                                                              \
    _Pragma("unroll")                                                         \
    for (int i = 0; i < 2; i++)                                               \
      *(ushort8*)&(AsX)[(i * 64 + srow) * 32 + sc8] = a8[i];                  \
  }

#define GEMM_COMPUTE(AsX, BsX)                                                \
  {                                                                           \
    short8 af[4], bfr[4];                                                     \
    _Pragma("unroll")                                                         \
    for (int mi = 0; mi < 4; mi++)                                            \
      af[mi] = *(const short8*)&(AsX)[(wm + mi * 16 + lc) * 32 + lg * 8];     \
    _Pragma("unroll")                                                         \
    for (int ni = 0; ni < 4; ni++)                                            \
      bfr[ni] = *(const short8*)&(BsX)[(wn + ni * 16 + lc) * 32 + lg * 8];    \
    __builtin_amdgcn_s_setprio(1);                                            \
    _Pragma("unroll")                                                         \
    for (int mi = 0; mi < 4; mi++)                                            \
      _Pragma("unroll")                                                       \
      for (int ni = 0; ni < 4; ni++)                                          \
        acc[mi][ni] = __builtin_amdgcn_mfma_f32_16x16x32_bf16(                \
            af[mi], bfr[ni], acc[mi][ni], 0, 0, 0);                           \
    __builtin_amdgcn_s_setprio(0);                                            \
  }

template<bool A_BF16, bool OUT_BF16>
__global__ __launch_bounds__(256)
void gemm_bt(const void* __restrict__ A0, const void* __restrict__ A1,
             const void* __restrict__ A2,
             const unsigned short* __restrict__ W0,
             const unsigned short* __restrict__ W1,
             const unsigned short* __restrict__ W2,
             void* __restrict__ C0, void* __restrict__ C1, void* __restrict__ C2)
{
    __shared__ unsigned short As0[128 * 32];   // 8 KB each, 32 KB total
    __shared__ unsigned short Bs0[128 * 32];
    __shared__ unsigned short As1[128 * 32];
    __shared__ unsigned short Bs1[128 * 32];

    const int tid  = threadIdx.x;
    const int bid  = blockIdx.x;
    const int x    = bid & 7, j = bid >> 3;
    const int z    = j / 48;            // 0..2 (QKV, grid 1152) or 0 (grid 384)
    const int r48  = j % 48;
    const int bm   = x * 8 + r48 / 6;
    const int bn   = r48 % 6;

    const int w    = tid >> 6, lane = tid & 63;
    const int lg   = lane >> 4, lc = lane & 15;
    const int wm   = (w >> 1) * 64, wn = (w & 1) * 64;

    const void* Av = (z == 0) ? A0 : (z == 1) ? A1 : A2;
    const unsigned short* Bw = (z == 0) ? W0 : (z == 1) ? W1 : W2;
    void* Cv = (z == 0) ? C0 : (z == 1) ? C1 : C2;

    const float*          Af = (const float*)Av;
    const unsigned short* Ah = (const unsigned short*)Av;

    // staging geometry: row tid>>2 (two 64-row chunks), col (tid&3)*8
    const int srow = tid >> 2;
    const int sc8  = (tid & 3) * 8;

    const unsigned short* gB  = &Bw[(size_t)(bn * 128 + srow) * H_ + sc8];
    const unsigned short* gAh = A_BF16 ? &Ah[(size_t)(bm * 128 + srow) * H_ + sc8] : nullptr;
    const float*          gAf = A_BF16 ? nullptr : &Af[(size_t)(bm * 128 + srow) * H_ + sc8];

    f32x4 acc[4][4] = {};
    ushort8 a8[2];    // prefetched+converted A (fp32 path)

    // ---- prologue: stage tile 0 into buf 0 ----
    GEMM_ISSUE(As0, Bs0, 0);
    GEMM_WRITE_A(As0);
    __syncthreads();

    // ---- main loop: 11 x 2 tiles (tiles 0..21), prefetching t+1, t+2 ----
#pragma unroll 1
    for (int t = 0; t < 22; t += 2) {
        GEMM_ISSUE(As1, Bs1, (t + 1) * 32);
        GEMM_COMPUTE(As0, Bs0);
        GEMM_WRITE_A(As1);
        __syncthreads();

        GEMM_ISSUE(As0, Bs0, (t + 2) * 32);
        GEMM_COMPUTE(As1, Bs1);
        GEMM_WRITE_A(As0);
        __syncthreads();
    }

    // ---- tail: tiles 22 (in buf0) and 23 ----
    GEMM_ISSUE(As1, Bs1, 23 * 32);
    GEMM_COMPUTE(As0, Bs0);
    GEMM_WRITE_A(As1);
    __syncthreads();
    GEMM_COMPUTE(As1, Bs1);

#pragma unroll
    for (int mi = 0; mi < 4; mi++)
#pragma unroll
        for (int ni = 0; ni < 4; ni++)
#pragma unroll
            for (int reg = 0; reg < 4; reg++) {
                const int row = bm * 128 + wm + mi * 16 + lg * 4 + reg;
                const int col = bn * 128 + wn + ni * 16 + lc;
                if (OUT_BF16)
                    ((unsigned short*)Cv)[(size_t)row * H_ + col] = f2bf(acc[mi][ni][reg]);
                else
                    ((float*)Cv)[(size_t)row * H_ + col] = acc[mi][ni][reg];
            }
}

// ---------------------------------------------------------------------------
// V transpose: vb[B,S,H] -> vt[B,NH,DK,S]  (per head: [key][d] -> [d][key]).
// ---------------------------------------------------------------------------
__global__ __launch_bounds__(256)
void transpose_v(const unsigned short* __restrict__ v,
                 unsigned short* __restrict__ vt)
{
    __shared__ unsigned short T[64][72];
    const int tid = threadIdx.x;
    const int st0 = blockIdx.x, h = blockIdx.y, b = blockIdx.z;
    const int r = tid >> 2, d0 = (tid & 3) * 16, g = tid & 3;

    const unsigned short* src = &v[(size_t)(b * S_ + st0 * 64 + r) * H_ + h * DK_ + d0];
    const ushort8 v0 = *(const ushort8*)src;
    const ushort8 v1 = *(const ushort8*)(src + 8);
    const int colv = r ^ (g << 4);
#pragma unroll
    for (int jj = 0; jj < 8; jj++) T[d0 + jj][colv]     = v0[jj];
#pragma unroll
    for (int jj = 0; jj < 8; jj++) T[d0 + 8 + jj][colv] = v1[jj];
    __syncthreads();

    const size_t ob = ((size_t)(b * NH_ + h) * DK_) * S_ + st0 * 64;
#pragma unroll
    for (int half = 0; half < 2; half++) {
        const int ci = half * 256 + tid;
        const int d = ci >> 3, kc = ci & 7;
        const int sw = ((d >> 4) & 3) << 4;
        const ushort8 val = *(const ushort8*)&T[d][(kc * 8) ^ sw];
        *(ushort8*)&vt[ob + (size_t)d * S_ + kc * 8] = val;
    }
}

// ---------------------------------------------------------------------------
// Flash attention v5 (round-9, unchanged — best measured ~49 us): K + V^T
// staged in LDS (vectorized, padded-72 conflict-free), swapped QK^T,
// static-max softmax (p = exp2(s)), lane-local l partials reduced once after
// the loop, cvt_pk P-pack + double-shuffle P-exchange.
// ---------------------------------------------------------------------------
__global__ __launch_bounds__(256)
void attn(const unsigned short* __restrict__ q,
          const unsigned short* __restrict__ k,
          const unsigned short* __restrict__ vt,
          unsigned short* __restrict__ c)
{
    __shared__ unsigned short Ks[64][72];
    __shared__ unsigned short Vs[64][72];   // Vs[d][key], direct rows of vt

    const int tid  = threadIdx.x;
    const int qt   = blockIdx.x, h = blockIdx.y, b = blockIdx.z;
    const int wid  = tid >> 6;
    const int lane = tid & 63;
    const int lg   = lane >> 4, lc = lane & 15;
    const int r    = tid >> 2;
    const int g    = tid & 3;
    const int d0   = g * 16;
    const size_t base = (size_t)b * S_ * H_ + (size_t)h * DK_;
    const size_t vtb  = (size_t)(b * NH_ + h) * DK_ * S_;

    short8 aq[2][2];
#pragma unroll
    for (int m = 0; m < 2; m++)
#pragma unroll
        for (int ks = 0; ks < 2; ks++)
            aq[m][ks] = *(const short8*)
                &q[base + (size_t)(qt * 128 + wid * 32 + m * 16 + lc) * H_ + ks * 32 + lg * 8];

    f32x4 o[2][4] = {};
    float lsum[2] = {0.f, 0.f};

    for (int kt = 0; kt < S_ / 64; kt++) {
        {
            const unsigned short* ksrc = &k[base + (size_t)(kt * 64 + r) * H_ + d0];
            *(ushort8*)&Ks[r][d0]     = *(const ushort8*)ksrc;
            *(ushort8*)&Ks[r][d0 + 8] = *(const ushort8*)(ksrc + 8);
            const unsigned short* vsrc = &vt[vtb + (size_t)r * S_ + kt * 64 + d0];
            *(ushort8*)&Vs[r][d0]     = *(const ushort8*)vsrc;
            *(ushort8*)&Vs[r][d0 + 8] = *(const ushort8*)(vsrc + 8);
        }
        __syncthreads();

        f32x4 st[2][4] = {};
        __builtin_amdgcn_s_setprio(1);
#pragma unroll
        for (int ni = 0; ni < 4; ni++)
#pragma unroll
            for (int ks = 0; ks < 2; ks++) {
                const short8 bk = *(const short8*)&Ks[ni * 16 + lc][ks * 32 + lg * 8];
                st[0][ni] = __builtin_amdgcn_mfma_f32_16x16x32_bf16(bk, aq[0][ks], st[0][ni], 0, 0, 0);
                st[1][ni] = __builtin_amdgcn_mfma_f32_16x16x32_bf16(bk, aq[1][ks], st[1][ni], 0, 0, 0);
            }
        __builtin_amdgcn_s_setprio(0);

        unsigned pw[2][4][2];
#pragma unroll
        for (int m = 0; m < 2; m++) {
#pragma unroll
            for (int ni = 0; ni < 4; ni++) {
#pragma unroll
                for (int reg = 0; reg < 4; reg++) {
                    const float pp = exp2f(st[m][ni][reg]);
                    st[m][ni][reg] = pp;
                    lsum[m] += pp;
                }
                pw[m][ni][0] = cvtpk_bf16(st[m][ni][0], st[m][ni][1]);
                pw[m][ni][1] = cvtpk_bf16(st[m][ni][2], st[m][ni][3]);
            }
        }

        const int sl0 = lc + ((lg & 1) << 5);
        const int sl1 = sl0 + 16;
        const bool hi = (lg >> 1) != 0;
        short8 pa[2][2];
#pragma unroll
        for (int m = 0; m < 2; m++)
#pragma unroll
            for (int ks = 0; ks < 2; ks++) {
                const unsigned lo0 = pw[m][2 * ks][0],     lo1 = pw[m][2 * ks][1];
                const unsigned hi0 = pw[m][2 * ks + 1][0], hi1 = pw[m][2 * ks + 1][1];
                union { unsigned u[4]; short8 s8; } pk;
                const unsigned a0l = __shfl(lo0, sl0, 64), a0h = __shfl(hi0, sl0, 64);
                const unsigned a1l = __shfl(lo1, sl0, 64), a1h = __shfl(hi1, sl0, 64);
                const unsigned a2l = __shfl(lo0, sl1, 64), a2h = __shfl(hi0, sl1, 64);
                const unsigned a3l = __shfl(lo1, sl1, 64), a3h = __shfl(hi1, sl1, 64);
                pk.u[0] = hi ? a0h : a0l;
                pk.u[1] = hi ? a1h : a1l;
                pk.u[2] = hi ? a2h : a2l;
                pk.u[3] = hi ? a3h : a3l;
                pa[m][ks] = pk.s8;
            }

        __builtin_amdgcn_s_setprio(1);
#pragma unroll
        for (int ni = 0; ni < 4; ni++)
#pragma unroll
            for (int ks = 0; ks < 2; ks++) {
                const short8 bv = *(const short8*)&Vs[ni * 16 + lc][ks * 32 + lg * 8];
                o[0][ni] = __builtin_amdgcn_mfma_f32_16x16x32_bf16(pa[0][ks], bv, o[0][ni], 0, 0, 0);
                o[1][ni] = __builtin_amdgcn_mfma_f32_16x16x32_bf16(pa[1][ks], bv, o[1][ni], 0, 0, 0);
            }
        __builtin_amdgcn_s_setprio(0);
        __syncthreads();
    }

#pragma unroll
    for (int m = 0; m < 2; m++) {
        float l = lsum[m];
        l += __shfl_xor(l, 16, 64);
        l += __shfl_xor(l, 32, 64);
        const float iv = 1.0f / l;
#pragma unroll
        for (int reg = 0; reg < 4; reg++) {
            const float ivr = __shfl(iv, lg * 4 + reg, 64);
            const int row = qt * 128 + wid * 32 + m * 16 + lg * 4 + reg;
#pragma unroll
            for (int ni = 0; ni < 4; ni++)
                c[base + (size_t)row * H_ + ni * 16 + lc] = f2bf(o[m][ni][reg] * ivr);
        }
    }
}

// ---------------------------------------------------------------------------
extern "C" void kernel_launch(void* const* d_in, const int* in_sizes, int n_in,
                              void* d_out, int out_size, void* d_ws, size_t ws_size,
                              hipStream_t stream)
{
    const float* Q  = (const float*)d_in[0];
    const float* K  = (const float*)d_in[1];
    const float* V  = (const float*)d_in[2];
    const float* Wq = (const float*)d_in[3];
    const float* Wk = (const float*)d_in[4];
    const float* Wv = (const float*)d_in[5];
    const float* Wo = (const float*)d_in[6];

    unsigned short* qb = (unsigned short*)d_ws;
    unsigned short* kb = qb + (size_t)M_ * H_;
    unsigned short* vb = kb + (size_t)M_ * H_;
    unsigned short* vtb = vb + (size_t)M_ * H_;   // transposed V
    unsigned short* cb  = vb;                      // vb dead after transpose
    unsigned short* wq = vtb + (size_t)M_ * H_;
    unsigned short* wk = wq + (size_t)H_ * H_;
    unsigned short* wv = wk + (size_t)H_ * H_;
    unsigned short* wo = wv + (size_t)H_ * H_;

    cvt_w<<<dim3(H_ * H_ / 4 / 256, 4), 256, 0, stream>>>(
        Wq, Wk, Wv, Wo, wq, wk, wv, wo);

    // fused QKV projections: 1152 blocks, XCD-swizzled inside the kernel
    gemm_bt<false, true><<<dim3(64 * 6 * 3), 256, 0, stream>>>(
        Q, K, V, wq, wk, wv, qb, kb, vb);

    transpose_v<<<dim3(S_ / 64, NH_, B_), 256, 0, stream>>>(vb, vtb);

    attn<<<dim3(S_ / 128, NH_, B_), 256, 0, stream>>>(qb, kb, vtb, cb);

    // output projection: 384 blocks (z = 0), bf16 A via global_load_lds
    gemm_bt<true, false><<<dim3(64 * 6), 256, 0, stream>>>(
        cb, cb, cb, wo, wo, wo, d_out, d_out, d_out);
}

// Round 14
// 151.586 us; speedup vs baseline: 1.2209x; 1.0125x over previous
//
#include <hip/hip_runtime.h>
#include <hip/hip_bf16.h>

#define B_   8
#define S_   1024
#define H_   768
#define NH_  12
#define DK_  64
#define M_   (B_ * S_)   // 8192

typedef __attribute__((ext_vector_type(8))) short          short8;
typedef __attribute__((ext_vector_type(8))) unsigned short ushort8;
typedef __attribute__((ext_vector_type(4))) unsigned short ushort4v;
typedef __attribute__((ext_vector_type(4))) float          f32x4;

__device__ __forceinline__ unsigned short f2bf(float x) {
    union { __hip_bfloat16 h; unsigned short u; } r;
    r.h = __float2bfloat16(x);
    return r.u;
}

__device__ __forceinline__ unsigned cvtpk_bf16(float lo, float hi) {
    unsigned r;
    asm("v_cvt_pk_bf16_f32 %0, %1, %2" : "=v"(r) : "v"(lo), "v"(hi));
    return r;
}

__device__ __forceinline__ void glds16(const unsigned short* g, unsigned short* l) {
    __builtin_amdgcn_global_load_lds(
        (const __attribute__((address_space(1))) unsigned int*)g,
        (__attribute__((address_space(3))) unsigned int*)l, 16, 0, 0);
}

// ---------------------------------------------------------------------------
// One-shot convert of the 4 weight matrices to bf16 (Wq pre-scaled by
// log2(e)/sqrt(DK) so attention scores land directly in exp2 domain).
// ---------------------------------------------------------------------------
__global__ __launch_bounds__(256)
void cvt_w(const float* __restrict__ w0, const float* __restrict__ w1,
           const float* __restrict__ w2, const float* __restrict__ w3,
           unsigned short* __restrict__ o0, unsigned short* __restrict__ o1,
           unsigned short* __restrict__ o2, unsigned short* __restrict__ o3)
{
    const int wsel = blockIdx.y;
    const float* src = (wsel == 0) ? w0 : (wsel == 1) ? w1 : (wsel == 2) ? w2 : w3;
    unsigned short* dst = (wsel == 0) ? o0 : (wsel == 1) ? o1 : (wsel == 2) ? o2 : o3;
    const float s = (wsel == 0) ? 0.125f * 1.44269504089f : 1.0f;
    const int i = blockIdx.x * 256 + threadIdx.x;
    const float4 x = ((const float4*)src)[i];
    ushort4v o;
    o[0] = f2bf(x.x * s); o[1] = f2bf(x.y * s);
    o[2] = f2bf(x.z * s); o[3] = f2bf(x.w * s);
    ((ushort4v*)dst)[i] = o;
}

// ---------------------------------------------------------------------------
// y[M,N] = x[M,K] @ W[N,K]^T.  128x128 tile, BK=32, 4 waves x (4x4) frags.
// PREFETCHED 2-phase, statically-named double buffers.  ROUND-14 FIX (T14
// done right): the fp32-A path holds RAW float4 in registers through the
// MFMA phase; f2bf conversion happens only in WRITE_A (after compute).
// Round 13 converted inline with the loads, which forced the vmcnt wait
// BEFORE the MFMA phase -> A latency never hidden (VALUBusy fell 25->18.6).
// Per phase: ISSUE(next: B async DMA, A-fp32 raw->regs) -> COMPUTE(cur)
//            -> cvt+WRITE_A(next) -> barrier.
// XCD-colocating 1D-grid swizzle (bid&7 -> XCD) kept.
// ---------------------------------------------------------------------------
#define GEMM_ISSUE(AsX, BsX, k0)                                              \
  {                                                                           \
    glds16(gB + (k0), (BsX) + w * 512);                                       \
    glds16(gB + (size_t)64 * H_ + (k0), (BsX) + 2048 + w * 512);              \
    if (A_BF16) {                                                             \
      glds16(gAh + (k0), (AsX) + w * 512);                                    \
      glds16(gAh + (size_t)64 * H_ + (k0), (AsX) + 2048 + w * 512);           \
    } else {                                                                  \
      _Pragma("unroll")                                                       \
      for (int i = 0; i < 2; i++) {                                           \
        araw[2 * i]     = *(const float4*)(gAf + (size_t)i * 64 * H_ + (k0)); \
        araw[2 * i + 1] = *(const float4*)(gAf + (size_t)i * 64 * H_ + (k0) + 4);\
      }                                                                       \
    }                                                                         \
  }

#define GEMM_WRITE_A(AsX)                                                     \
  if (!A_BF16) {                                                              \
    _Pragma("unroll")                                                         \
    for (int i = 0; i < 2; i++) {                                             \
      ushort8 o8;                                                             \
      o8[0] = f2bf(araw[2 * i].x);     o8[1] = f2bf(araw[2 * i].y);           \
      o8[2] = f2bf(araw[2 * i].z);     o8[3] = f2bf(araw[2 * i].w);           \
      o8[4] = f2bf(araw[2 * i + 1].x); o8[5] = f2bf(araw[2 * i + 1].y);       \
      o8[6] = f2bf(araw[2 * i + 1].z); o8[7] = f2bf(araw[2 * i + 1].w);       \
      *(ushort8*)&(AsX)[(i * 64 + srow) * 32 + sc8] = o8;                     \
    }                                                                         \
  }

#define GEMM_COMPUTE(AsX, BsX)                                                \
  {                                                                           \
    short8 af[4], bfr[4];                                                     \
    _Pragma("unroll")                                                         \
    for (int mi = 0; mi < 4; mi++)                                            \
      af[mi] = *(const short8*)&(AsX)[(wm + mi * 16 + lc) * 32 + lg * 8];     \
    _Pragma("unroll")                                                         \
    for (int ni = 0; ni < 4; ni++)                                            \
      bfr[ni] = *(const short8*)&(BsX)[(wn + ni * 16 + lc) * 32 + lg * 8];    \
    __builtin_amdgcn_s_setprio(1);                                            \
    _Pragma("unroll")                                                         \
    for (int mi = 0; mi < 4; mi++)                                            \
      _Pragma("unroll")                                                       \
      for (int ni = 0; ni < 4; ni++)                                          \
        acc[mi][ni] = __builtin_amdgcn_mfma_f32_16x16x32_bf16(                \
            af[mi], bfr[ni], acc[mi][ni], 0, 0, 0);                           \
    __builtin_amdgcn_s_setprio(0);                                            \
  }

template<bool A_BF16, bool OUT_BF16>
__global__ __launch_bounds__(256)
void gemm_bt(const void* __restrict__ A0, const void* __restrict__ A1,
             const void* __restrict__ A2,
             const unsigned short* __restrict__ W0,
             const unsigned short* __restrict__ W1,
             const unsigned short* __restrict__ W2,
             void* __restrict__ C0, void* __restrict__ C1, void* __restrict__ C2)
{
    __shared__ unsigned short As0[128 * 32];   // 8 KB each, 32 KB total
    __shared__ unsigned short Bs0[128 * 32];
    __shared__ unsigned short As1[128 * 32];
    __shared__ unsigned short Bs1[128 * 32];

    const int tid  = threadIdx.x;
    const int bid  = blockIdx.x;
    const int x    = bid & 7, j = bid >> 3;
    const int z    = j / 48;            // 0..2 (QKV, grid 1152) or 0 (grid 384)
    const int r48  = j % 48;
    const int bm   = x * 8 + r48 / 6;
    const int bn   = r48 % 6;

    const int w    = tid >> 6, lane = tid & 63;
    const int lg   = lane >> 4, lc = lane & 15;
    const int wm   = (w >> 1) * 64, wn = (w & 1) * 64;

    const void* Av = (z == 0) ? A0 : (z == 1) ? A1 : A2;
    const unsigned short* Bw = (z == 0) ? W0 : (z == 1) ? W1 : W2;
    void* Cv = (z == 0) ? C0 : (z == 1) ? C1 : C2;

    const float*          Af = (const float*)Av;
    const unsigned short* Ah = (const unsigned short*)Av;

    // staging geometry: row tid>>2 (two 64-row chunks), col (tid&3)*8
    const int srow = tid >> 2;
    const int sc8  = (tid & 3) * 8;

    const unsigned short* gB  = &Bw[(size_t)(bn * 128 + srow) * H_ + sc8];
    const unsigned short* gAh = A_BF16 ? &Ah[(size_t)(bm * 128 + srow) * H_ + sc8] : nullptr;
    const float*          gAf = A_BF16 ? nullptr : &Af[(size_t)(bm * 128 + srow) * H_ + sc8];

    f32x4 acc[4][4] = {};
    float4 araw[4];   // RAW prefetched A (fp32 path); cvt deferred to WRITE_A

    // ---- prologue: stage tile 0 into buf 0 ----
    GEMM_ISSUE(As0, Bs0, 0);
    GEMM_WRITE_A(As0);
    __syncthreads();

    // ---- main loop: tiles 0..21 computed, prefetching t+1, t+2 ----
#pragma unroll 1
    for (int t = 0; t < 22; t += 2) {
        GEMM_ISSUE(As1, Bs1, (t + 1) * 32);
        GEMM_COMPUTE(As0, Bs0);
        GEMM_WRITE_A(As1);
        __syncthreads();

        GEMM_ISSUE(As0, Bs0, (t + 2) * 32);
        GEMM_COMPUTE(As1, Bs1);
        GEMM_WRITE_A(As0);
        __syncthreads();
    }

    // ---- tail: tiles 22 (in buf0) and 23 ----
    GEMM_ISSUE(As1, Bs1, 23 * 32);
    GEMM_COMPUTE(As0, Bs0);
    GEMM_WRITE_A(As1);
    __syncthreads();
    GEMM_COMPUTE(As1, Bs1);

#pragma unroll
    for (int mi = 0; mi < 4; mi++)
#pragma unroll
        for (int ni = 0; ni < 4; ni++)
#pragma unroll
            for (int reg = 0; reg < 4; reg++) {
                const int row = bm * 128 + wm + mi * 16 + lg * 4 + reg;
                const int col = bn * 128 + wn + ni * 16 + lc;
                if (OUT_BF16)
                    ((unsigned short*)Cv)[(size_t)row * H_ + col] = f2bf(acc[mi][ni][reg]);
                else
                    ((float*)Cv)[(size_t)row * H_ + col] = acc[mi][ni][reg];
            }
}

// ---------------------------------------------------------------------------
// V transpose: vb[B,S,H] -> vt[B,NH,DK,S]  (per head: [key][d] -> [d][key]).
// ---------------------------------------------------------------------------
__global__ __launch_bounds__(256)
void transpose_v(const unsigned short* __restrict__ v,
                 unsigned short* __restrict__ vt)
{
    __shared__ unsigned short T[64][72];
    const int tid = threadIdx.x;
    const int st0 = blockIdx.x, h = blockIdx.y, b = blockIdx.z;
    const int r = tid >> 2, d0 = (tid & 3) * 16, g = tid & 3;

    const unsigned short* src = &v[(size_t)(b * S_ + st0 * 64 + r) * H_ + h * DK_ + d0];
    const ushort8 v0 = *(const ushort8*)src;
    const ushort8 v1 = *(const ushort8*)(src + 8);
    const int colv = r ^ (g << 4);
#pragma unroll
    for (int jj = 0; jj < 8; jj++) T[d0 + jj][colv]     = v0[jj];
#pragma unroll
    for (int jj = 0; jj < 8; jj++) T[d0 + 8 + jj][colv] = v1[jj];
    __syncthreads();

    const size_t ob = ((size_t)(b * NH_ + h) * DK_) * S_ + st0 * 64;
#pragma unroll
    for (int half = 0; half < 2; half++) {
        const int ci = half * 256 + tid;
        const int d = ci >> 3, kc = ci & 7;
        const int sw = ((d >> 4) & 3) << 4;
        const ushort8 val = *(const ushort8*)&T[d][(kc * 8) ^ sw];
        *(ushort8*)&vt[ob + (size_t)d * S_ + kc * 8] = val;
    }
}

// ---------------------------------------------------------------------------
// Flash attention v5 (round-9, unchanged — best measured ~49 us): K + V^T
// staged in LDS (vectorized, padded-72 conflict-free), swapped QK^T,
// static-max softmax (p = exp2(s)), lane-local l partials reduced once after
// the loop, cvt_pk P-pack + double-shuffle P-exchange.
// ---------------------------------------------------------------------------
__global__ __launch_bounds__(256)
void attn(const unsigned short* __restrict__ q,
          const unsigned short* __restrict__ k,
          const unsigned short* __restrict__ vt,
          unsigned short* __restrict__ c)
{
    __shared__ unsigned short Ks[64][72];
    __shared__ unsigned short Vs[64][72];   // Vs[d][key], direct rows of vt

    const int tid  = threadIdx.x;
    const int qt   = blockIdx.x, h = blockIdx.y, b = blockIdx.z;
    const int wid  = tid >> 6;
    const int lane = tid & 63;
    const int lg   = lane >> 4, lc = lane & 15;
    const int r    = tid >> 2;
    const int g    = tid & 3;
    const int d0   = g * 16;
    const size_t base = (size_t)b * S_ * H_ + (size_t)h * DK_;
    const size_t vtb  = (size_t)(b * NH_ + h) * DK_ * S_;

    short8 aq[2][2];
#pragma unroll
    for (int m = 0; m < 2; m++)
#pragma unroll
        for (int ks = 0; ks < 2; ks++)
            aq[m][ks] = *(const short8*)
                &q[base + (size_t)(qt * 128 + wid * 32 + m * 16 + lc) * H_ + ks * 32 + lg * 8];

    f32x4 o[2][4] = {};
    float lsum[2] = {0.f, 0.f};

    for (int kt = 0; kt < S_ / 64; kt++) {
        {
            const unsigned short* ksrc = &k[base + (size_t)(kt * 64 + r) * H_ + d0];
            *(ushort8*)&Ks[r][d0]     = *(const ushort8*)ksrc;
            *(ushort8*)&Ks[r][d0 + 8] = *(const ushort8*)(ksrc + 8);
            const unsigned short* vsrc = &vt[vtb + (size_t)r * S_ + kt * 64 + d0];
            *(ushort8*)&Vs[r][d0]     = *(const ushort8*)vsrc;
            *(ushort8*)&Vs[r][d0 + 8] = *(const ushort8*)(vsrc + 8);
        }
        __syncthreads();

        f32x4 st[2][4] = {};
        __builtin_amdgcn_s_setprio(1);
#pragma unroll
        for (int ni = 0; ni < 4; ni++)
#pragma unroll
            for (int ks = 0; ks < 2; ks++) {
                const short8 bk = *(const short8*)&Ks[ni * 16 + lc][ks * 32 + lg * 8];
                st[0][ni] = __builtin_amdgcn_mfma_f32_16x16x32_bf16(bk, aq[0][ks], st[0][ni], 0, 0, 0);
                st[1][ni] = __builtin_amdgcn_mfma_f32_16x16x32_bf16(bk, aq[1][ks], st[1][ni], 0, 0, 0);
            }
        __builtin_amdgcn_s_setprio(0);

        unsigned pw[2][4][2];
#pragma unroll
        for (int m = 0; m < 2; m++) {
#pragma unroll
            for (int ni = 0; ni < 4; ni++) {
#pragma unroll
                for (int reg = 0; reg < 4; reg++) {
                    const float pp = exp2f(st[m][ni][reg]);
                    st[m][ni][reg] = pp;
                    lsum[m] += pp;
                }
                pw[m][ni][0] = cvtpk_bf16(st[m][ni][0], st[m][ni][1]);
                pw[m][ni][1] = cvtpk_bf16(st[m][ni][2], st[m][ni][3]);
            }
        }

        const int sl0 = lc + ((lg & 1) << 5);
        const int sl1 = sl0 + 16;
        const bool hi = (lg >> 1) != 0;
        short8 pa[2][2];
#pragma unroll
        for (int m = 0; m < 2; m++)
#pragma unroll
            for (int ks = 0; ks < 2; ks++) {
                const unsigned lo0 = pw[m][2 * ks][0],     lo1 = pw[m][2 * ks][1];
                const unsigned hi0 = pw[m][2 * ks + 1][0], hi1 = pw[m][2 * ks + 1][1];
                union { unsigned u[4]; short8 s8; } pk;
                const unsigned a0l = __shfl(lo0, sl0, 64), a0h = __shfl(hi0, sl0, 64);
                const unsigned a1l = __shfl(lo1, sl0, 64), a1h = __shfl(hi1, sl0, 64);
                const unsigned a2l = __shfl(lo0, sl1, 64), a2h = __shfl(hi0, sl1, 64);
                const unsigned a3l = __shfl(lo1, sl1, 64), a3h = __shfl(hi1, sl1, 64);
                pk.u[0] = hi ? a0h : a0l;
                pk.u[1] = hi ? a1h : a1l;
                pk.u[2] = hi ? a2h : a2l;
                pk.u[3] = hi ? a3h : a3l;
                pa[m][ks] = pk.s8;
            }

        __builtin_amdgcn_s_setprio(1);
#pragma unroll
        for (int ni = 0; ni < 4; ni++)
#pragma unroll
            for (int ks = 0; ks < 2; ks++) {
                const short8 bv = *(const short8*)&Vs[ni * 16 + lc][ks * 32 + lg * 8];
                o[0][ni] = __builtin_amdgcn_mfma_f32_16x16x32_bf16(pa[0][ks], bv, o[0][ni], 0, 0, 0);
                o[1][ni] = __builtin_amdgcn_mfma_f32_16x16x32_bf16(pa[1][ks], bv, o[1][ni], 0, 0, 0);
            }
        __builtin_amdgcn_s_setprio(0);
        __syncthreads();
    }

#pragma unroll
    for (int m = 0; m < 2; m++) {
        float l = lsum[m];
        l += __shfl_xor(l, 16, 64);
        l += __shfl_xor(l, 32, 64);
        const float iv = 1.0f / l;
#pragma unroll
        for (int reg = 0; reg < 4; reg++) {
            const float ivr = __shfl(iv, lg * 4 + reg, 64);
            const int row = qt * 128 + wid * 32 + m * 16 + lg * 4 + reg;
#pragma unroll
            for (int ni = 0; ni < 4; ni++)
                c[base + (size_t)row * H_ + ni * 16 + lc] = f2bf(o[m][ni][reg] * ivr);
        }
    }
}

// ---------------------------------------------------------------------------
extern "C" void kernel_launch(void* const* d_in, const int* in_sizes, int n_in,
                              void* d_out, int out_size, void* d_ws, size_t ws_size,
                              hipStream_t stream)
{
    const float* Q  = (const float*)d_in[0];
    const float* K  = (const float*)d_in[1];
    const float* V  = (const float*)d_in[2];
    const float* Wq = (const float*)d_in[3];
    const float* Wk = (const float*)d_in[4];
    const float* Wv = (const float*)d_in[5];
    const float* Wo = (const float*)d_in[6];

    unsigned short* qb = (unsigned short*)d_ws;
    unsigned short* kb = qb + (size_t)M_ * H_;
    unsigned short* vb = kb + (size_t)M_ * H_;
    unsigned short* vtb = vb + (size_t)M_ * H_;   // transposed V
    unsigned short* cb  = vb;                      // vb dead after transpose
    unsigned short* wq = vtb + (size_t)M_ * H_;
    unsigned short* wk = wq + (size_t)H_ * H_;
    unsigned short* wv = wk + (size_t)H_ * H_;
    unsigned short* wo = wv + (size_t)H_ * H_;

    cvt_w<<<dim3(H_ * H_ / 4 / 256, 4), 256, 0, stream>>>(
        Wq, Wk, Wv, Wo, wq, wk, wv, wo);

    // fused QKV projections: 1152 blocks, XCD-swizzled inside the kernel
    gemm_bt<false, true><<<dim3(64 * 6 * 3), 256, 0, stream>>>(
        Q, K, V, wq, wk, wv, qb, kb, vb);

    transpose_v<<<dim3(S_ / 64, NH_, B_), 256, 0, stream>>>(vb, vtb);

    attn<<<dim3(S_ / 128, NH_, B_), 256, 0, stream>>>(qb, kb, vtb, cb);

    // output projection: 384 blocks (z = 0), bf16 A via global_load_lds
    gemm_bt<true, false><<<dim3(64 * 6), 256, 0, stream>>>(
        cb, cb, cb, wo, wo, wo, d_out, d_out, d_out);
}